// Round 11
// baseline (863.142 us; speedup 1.0000x reference)
//
#include <hip/hip_runtime.h>

#define N_NODES 100000
#define M_EDGES 500000
#define D 128
#define SLOPE 0.01f
#define EPS 1e-5f

typedef __attribute__((ext_vector_type(8))) short bf16x8;
typedef __attribute__((ext_vector_type(4))) float f32x4;
typedef __attribute__((ext_vector_type(4))) unsigned int u32x4;

__device__ __forceinline__ unsigned short f2bf(float f) {
    union { float f; unsigned u; } v; v.f = f;
    unsigned r = v.u + 0x7FFF + ((v.u >> 16) & 1);   // RNE
    return (unsigned short)(r >> 16);
}
__device__ __forceinline__ float bf2f(unsigned short u) {
    union { unsigned u; float f; } v; v.u = ((unsigned)u) << 16; return v.f;
}
__device__ __forceinline__ u32x4 pack8v(f32x4 a, f32x4 b) {
    u32x4 r;
    r.x = ((unsigned)f2bf(a.y) << 16) | f2bf(a.x);
    r.y = ((unsigned)f2bf(a.w) << 16) | f2bf(a.z);
    r.z = ((unsigned)f2bf(b.y) << 16) | f2bf(b.x);
    r.w = ((unsigned)f2bf(b.w) << 16) | f2bf(b.z);
    return r;
}
// extract bf16 element nt (0..7) of a u32x4 as float (nt compile-time)
#define GXT(v, nt) bf2f((unsigned short)(((nt) & 1) ? ((v)[(nt) >> 1] >> 16) : ((v)[(nt) >> 1] & 0xffff)))

// ---------------------------------------------------------------------------
// Weight pre-convert: fp32 [L][K][128] -> bf16 fragment-major [L][K/32][8][64][8]
// ---------------------------------------------------------------------------
__global__ void wconv_kernel(const float* __restrict__ src, unsigned short* __restrict__ dst,
                             int K, int total)
{
    int i = blockIdx.x * 256 + threadIdx.x;
    if (i >= total) return;
    int layer_sz = K * 128;
    int l = i / layer_sz;
    int r = i - l * layer_sz;
    int j    = r & 7;
    int lane = (r >> 3) & 63;
    int nt   = (r >> 9) & 7;
    int kk   = r >> 12;
    int row  = kk * 32 + ((lane >> 4) << 3) + j;
    int col  = nt * 16 + (lane & 15);
    dst[i] = f2bf(src[(size_t)l * layer_sz + row * 128 + col]);
}

__global__ void h2b_kernel(const float* __restrict__ src, unsigned short* __restrict__ dst, int total8)
{
    int i = blockIdx.x * 256 + threadIdx.x;
    if (i >= total8) return;
    f32x4 a = ((const f32x4*)src)[2 * i];
    f32x4 b = ((const f32x4*)src)[2 * i + 1];
    ((u32x4*)dst)[i] = pack8v(a, b);
}

// ---------------------------------------------------------------------------
// CSR build
// ---------------------------------------------------------------------------
__global__ void count_kernel(const int* __restrict__ ht, int* __restrict__ cnt, int m)
{
    int e = blockIdx.x * 256 + threadIdx.x;
    if (e < m) {
        atomicAdd(&cnt[ht[2 * e]],     1);
        atomicAdd(&cnt[ht[2 * e + 1]], 1);
    }
}

__global__ void scanA_kernel(const int* __restrict__ cnt, int* __restrict__ partial,
                             int* __restrict__ bsum, int n)
{
    __shared__ int tmp[256];
    int t = threadIdx.x, i = blockIdx.x * 256 + t;
    int v = (i < n) ? cnt[i] : 0;
    tmp[t] = v;
    __syncthreads();
    for (int s = 1; s < 256; s <<= 1) {
        int x = (t >= s) ? tmp[t - s] : 0;
        __syncthreads();
        tmp[t] += x;
        __syncthreads();
    }
    if (i < n) partial[i] = tmp[t] - v;
    if (t == 255) bsum[blockIdx.x] = tmp[255];
}

__global__ void scanB_kernel(int* __restrict__ bsum, int nb)
{
    __shared__ int tmp[512];
    int t = threadIdx.x;
    int v = (t < nb) ? bsum[t] : 0;
    tmp[t] = v;
    __syncthreads();
    for (int s = 1; s < 512; s <<= 1) {
        int x = (t >= s) ? tmp[t - s] : 0;
        __syncthreads();
        tmp[t] += x;
        __syncthreads();
    }
    if (t < nb) bsum[t] = tmp[t] - v;
}

__global__ void scanC_kernel(const int* __restrict__ partial, const int* __restrict__ bsum,
                             int* __restrict__ off, int* __restrict__ pos, int n)
{
    int i = blockIdx.x * 256 + threadIdx.x;
    if (i < n) {
        int o = partial[i] + bsum[blockIdx.x];
        off[i] = o;
        pos[i] = o;
    }
    if (i == 0) off[n] = 2 * M_EDGES;
}

__global__ void fill_kernel(const int* __restrict__ ht, int* __restrict__ pos,
                            int* __restrict__ slotF, int* __restrict__ slotB, int m)
{
    int e = blockIdx.x * 256 + threadIdx.x;
    if (e < m) {
        int2 p = ((const int2*)ht)[e];
        slotF[e] = atomicAdd(&pos[p.y], 1);
        slotB[e] = atomicAdd(&pos[p.x], 1);
    }
}

// ---------------------------------------------------------------------------
// Dense HW GEMM: HW[n][512] = Hb @ [Wa | Wc | Wf_top | Wb_top]   (bf16 out,
// per-row fragment-permuted: within group, pos = c15*8 + nt).
// grid = (N/128) x 4 groups; 4 waves x 32 rows; B (128x128) staged in LDS.
// ---------------------------------------------------------------------------
__global__ __launch_bounds__(256, 2)
void hw_kernel(const unsigned short* __restrict__ Hb,
               const unsigned short* __restrict__ B0,
               const unsigned short* __restrict__ B1,
               const unsigned short* __restrict__ B2,
               const unsigned short* __restrict__ B3,
               unsigned short* __restrict__ HW)
{
    __shared__ unsigned short bsh[16384];   // 32 KB

    const int tid = threadIdx.x;
    const int wv  = tid >> 6;
    const int ln  = tid & 63;
    const int g   = ln >> 4;
    const int c15 = ln & 15;
    const int mb  = blockIdx.x >> 2;
    const int grp = blockIdx.x & 3;

    const unsigned short* Bsel = (grp == 0) ? B0 : (grp == 1) ? B1 : (grp == 2) ? B2 : B3;

    // stage B (4 kk-slices, linear copy: layouts identical)
    {
        const u32x4* bs = (const u32x4*)Bsel;
        u32x4* bd = (u32x4*)bsh;
#pragma unroll
        for (int it = 0; it < 8; ++it) bd[it * 256 + tid] = bs[it * 256 + tid];
    }

    const int rb = mb * 128 + wv * 32;
    const unsigned short* arow[2];
#pragma unroll
    for (int m = 0; m < 2; ++m) {
        int r = rb + m * 16 + c15;
        if (r >= N_NODES) r = N_NODES - 1;
        arow[m] = Hb + (size_t)r * 128;
    }
    __syncthreads();

    f32x4 acc[2][8];
#pragma unroll
    for (int m = 0; m < 2; ++m)
#pragma unroll
        for (int nt = 0; nt < 8; ++nt) acc[m][nt] = (f32x4){0.f, 0.f, 0.f, 0.f};

#pragma unroll
    for (int kk = 0; kk < 4; ++kk) {
        bf16x8 a[2];
#pragma unroll
        for (int m = 0; m < 2; ++m) a[m] = *(const bf16x8*)(arow[m] + kk * 32 + g * 8);
#pragma unroll
        for (int nt = 0; nt < 8; ++nt) {
            bf16x8 b = *(const bf16x8*)(bsh + (kk * 8 + nt) * 512 + ln * 8);
#pragma unroll
            for (int m = 0; m < 2; ++m)
                acc[m][nt] = __builtin_amdgcn_mfma_f32_16x16x32_bf16(a[m], b, acc[m][nt], 0, 0, 0);
        }
    }

    // store permuted bf16: HW[rg*512 + grp*128 + c15*8 .. +8)
#pragma unroll
    for (int m = 0; m < 2; ++m) {
#pragma unroll
        for (int rr = 0; rr < 4; ++rr) {
            int rg = rb + m * 16 + g * 4 + rr;
            if (rg < N_NODES) {
                u32x4 o;
                o.x = ((unsigned)f2bf(acc[m][1][rr]) << 16) | f2bf(acc[m][0][rr]);
                o.y = ((unsigned)f2bf(acc[m][3][rr]) << 16) | f2bf(acc[m][2][rr]);
                o.z = ((unsigned)f2bf(acc[m][5][rr]) << 16) | f2bf(acc[m][4][rr]);
                o.w = ((unsigned)f2bf(acc[m][7][rr]) << 16) | f2bf(acc[m][6][rr]);
                *(u32x4*)(HW + (size_t)rg * 512 + grp * 128 + c15 * 8) = o;
            }
        }
    }
}

// ---------------------------------------------------------------------------
// Edge kernel: 1 wave, 32 edges (exact cover: 15625 blocks). NO gathers in
// k-loops (A = streamed E in LDS); H contributions added from precomputed HW
// via one-time 16B gathers. CSR slot stores.
// ---------------------------------------------------------------------------
template <bool E_F32, bool WRITE_E>
__global__ __launch_bounds__(64, 2)
void edge_mfma_kernel(const unsigned short* __restrict__ HW,
                      const float* __restrict__ E0,
                      const unsigned short* __restrict__ Ebf,
                      unsigned short* __restrict__ Eout,
                      const int* __restrict__ ht,
                      const unsigned short* __restrict__ Weu,
                      const unsigned short* __restrict__ Wf,
                      const unsigned short* __restrict__ Wb,
                      const float* __restrict__ beu,
                      const float* __restrict__ lneg, const float* __restrict__ lneb,
                      const float* __restrict__ bfw, const float* __restrict__ bbw,
                      const int* __restrict__ slotF, const int* __restrict__ slotB,
                      unsigned short* __restrict__ msg)
{
    __shared__ unsigned char en[8192];      // 32 E/en rows, bf16, XOR-swizzled

    const int ln  = threadIdx.x;
    const int g   = ln >> 4;
    const int c15 = ln & 15;
    const int ew0 = blockIdx.x * 32;

    const int slotFv = slotF[ew0 + (ln & 31)];
    const int slotBv = slotB[ew0 + (ln & 31)];

    // head/tail node ids for this lane's 8 C-rows
    int hid[2][4], tln[2][4];
#pragma unroll
    for (int m = 0; m < 2; ++m)
#pragma unroll
        for (int rr = 0; rr < 4; ++rr) {
            int2 p = ((const int2*)ht)[ew0 + m * 16 + g * 4 + rr];
            hid[m][rr] = p.x;
            tln[m][rr] = p.y;
        }

    // phase-1 HW gathers (issue early; consumed after k-loop)
    u32x4 ga[2][4], gc[2][4];
#pragma unroll
    for (int m = 0; m < 2; ++m)
#pragma unroll
        for (int rr = 0; rr < 4; ++rr) {
            ga[m][rr] = *(const u32x4*)(HW + (size_t)hid[m][rr] * 512 + c15 * 8);
            gc[m][rr] = *(const u32x4*)(HW + (size_t)tln[m][rr] * 512 + 128 + c15 * 8);
        }

    // ---- stage 32 E rows into LDS (bf16, XOR-swizzled) ----
#pragma unroll
    for (int it = 0; it < 8; ++it) {
        int lin = it * 1024 + ln * 16;
        int row = lin >> 8;
        int e   = ew0 + row;
        int elem = (lin & 255) >> 1;
        u32x4 pk;
        if (E_F32) {
            const float* s = E0 + (size_t)e * D + elem;
            pk = pack8v(*(const f32x4*)s, *(const f32x4*)(s + 4));
        } else {
            pk = *(const u32x4*)(Ebf + (size_t)e * D + elem);
        }
        *(u32x4*)(en + (lin ^ ((row & 7) << 4))) = pk;
    }

    const int ebase0 = c15 * 256 + g * 16;          // m=0 A-row base (bytes)
    const int ebase1 = (16 + c15) * 256 + g * 16;   // m=1
    const int swz    = (c15 & 7) << 4;

    f32x4 acc[2][8];

    // ======================= Phase 1: eu_E = E @ We (K=128) =================
#pragma unroll
    for (int m = 0; m < 2; ++m)
#pragma unroll
        for (int nt = 0; nt < 8; ++nt) acc[m][nt] = (f32x4){0.f, 0.f, 0.f, 0.f};
    {
        const u32x4* Wg = (const u32x4*)Weu;   // We = slices 4..7
        u32x4 bc[8];
        bf16x8 a0, a1, a0n, a1n;
#pragma unroll
        for (int nt = 0; nt < 8; ++nt) bc[nt] = Wg[4 * 512 + nt * 64 + ln];
        a0 = *(const bf16x8*)(en + (ebase0 ^ swz));
        a1 = *(const bf16x8*)(en + (ebase1 ^ swz));
#pragma unroll
        for (int kk = 0; kk < 4; ++kk) {
            if (kk < 3) {
                a0n = *(const bf16x8*)(en + ((ebase0 + (kk + 1) * 64) ^ swz));
                a1n = *(const bf16x8*)(en + ((ebase1 + (kk + 1) * 64) ^ swz));
            }
#pragma unroll
            for (int nt = 0; nt < 8; ++nt) {
                bf16x8 b = *(const bf16x8*)&bc[nt];
                acc[0][nt] = __builtin_amdgcn_mfma_f32_16x16x32_bf16(a0, b, acc[0][nt], 0, 0, 0);
                acc[1][nt] = __builtin_amdgcn_mfma_f32_16x16x32_bf16(a1, b, acc[1][nt], 0, 0, 0);
                if (kk < 3) bc[nt] = Wg[(5 + kk) * 512 + nt * 64 + ln];
            }
            a0 = a0n; a1 = a1n;
        }
    }

    // ==== + HW gathers + bias, leaky, + E_old, LayerNorm -> en ====
    {
        float be[8], lg[8], lb[8];
#pragma unroll
        for (int nt = 0; nt < 8; ++nt) {
            be[nt] = beu[nt * 16 + c15];
            lg[nt] = lneg[nt * 16 + c15];
            lb[nt] = lneb[nt * 16 + c15];
        }
#pragma unroll
        for (int m = 0; m < 2; ++m) {
            float s[4] = {0.f,0.f,0.f,0.f}, ss[4] = {0.f,0.f,0.f,0.f};
#pragma unroll
            for (int nt = 0; nt < 8; ++nt) {
#pragma unroll
                for (int r = 0; r < 4; ++r) {
                    int row = m * 16 + g * 4 + r;
                    float x = acc[m][nt][r] + GXT(ga[m][r], nt) + GXT(gc[m][r], nt) + be[nt];
                    x = (x >= 0.f) ? x : SLOPE * x;
                    int lin = row * 256 + (nt * 16 + c15) * 2;
                    x += bf2f(*(const unsigned short*)(en + (lin ^ ((row & 7) << 4))));
                    acc[m][nt][r] = x;
                    s[r] += x; ss[r] += x * x;
                }
            }
#pragma unroll
            for (int d = 1; d < 16; d <<= 1) {
#pragma unroll
                for (int r = 0; r < 4; ++r) {
                    s[r]  += __shfl_xor(s[r],  d);
                    ss[r] += __shfl_xor(ss[r], d);
                }
            }
            float mu[4], rs[4];
#pragma unroll
            for (int r = 0; r < 4; ++r) {
                mu[r] = s[r] * (1.0f / 128.0f);
                float var = ss[r] * (1.0f / 128.0f) - mu[r] * mu[r];
                rs[r] = rsqrtf(var + EPS);
            }
#pragma unroll
            for (int nt = 0; nt < 8; ++nt) {
#pragma unroll
                for (int r = 0; r < 4; ++r) {
                    int row = m * 16 + g * 4 + r;
                    float xn = (acc[m][nt][r] - mu[r]) * rs[r] * lg[nt] + lb[nt];
                    int lin = row * 256 + (nt * 16 + c15) * 2;
                    *(unsigned short*)(en + (lin ^ ((row & 7) << 4))) = f2bf(xn);
                }
            }
        }
    }

    // ---- write E_new (layer 0 only) ----
    if (WRITE_E) {
#pragma unroll
        for (int it = 0; it < 8; ++it) {
            int lin = it * 1024 + ln * 16;
            int row = lin >> 8;
            *(u32x4*)(Eout + (size_t)(ew0 + row) * D + ((lin & 255) >> 1)) =
                *(const u32x4*)(en + (lin ^ ((row & 7) << 4)));
        }
    }

    // =========== Phase 2: msg = HW_top[gathered] + en @ W_bot + bias ========
#pragma unroll 1
    for (int p = 0; p < 2; ++p) {
        const u32x4* Wg = (const u32x4*)(p ? Wb : Wf);   // bottom = slices 4..7
        const float* bias = p ? bbw : bfw;
        const int slotv = p ? slotBv : slotFv;

        // gathers: fwd msg adds HWf_top[head]; back msg adds HWb_top[tail]
        u32x4 gm[2][4];
#pragma unroll
        for (int m = 0; m < 2; ++m)
#pragma unroll
            for (int rr = 0; rr < 4; ++rr) {
                int node = p ? tln[m][rr] : hid[m][rr];
                gm[m][rr] = *(const u32x4*)(HW + (size_t)node * 512 + 256 + p * 128 + c15 * 8);
            }

#pragma unroll
        for (int m = 0; m < 2; ++m)
#pragma unroll
            for (int nt = 0; nt < 8; ++nt) acc[m][nt] = (f32x4){0.f, 0.f, 0.f, 0.f};
        {
            u32x4 bc[8];
            bf16x8 a0, a1, a0n, a1n;
#pragma unroll
            for (int nt = 0; nt < 8; ++nt) bc[nt] = Wg[4 * 512 + nt * 64 + ln];
            a0 = *(const bf16x8*)(en + (ebase0 ^ swz));
            a1 = *(const bf16x8*)(en + (ebase1 ^ swz));
#pragma unroll
            for (int kk = 0; kk < 4; ++kk) {
                if (kk < 3) {
                    a0n = *(const bf16x8*)(en + ((ebase0 + (kk + 1) * 64) ^ swz));
                    a1n = *(const bf16x8*)(en + ((ebase1 + (kk + 1) * 64) ^ swz));
                }
#pragma unroll
                for (int nt = 0; nt < 8; ++nt) {
                    bf16x8 b = *(const bf16x8*)&bc[nt];
                    acc[0][nt] = __builtin_amdgcn_mfma_f32_16x16x32_bf16(a0, b, acc[0][nt], 0, 0, 0);
                    acc[1][nt] = __builtin_amdgcn_mfma_f32_16x16x32_bf16(a1, b, acc[1][nt], 0, 0, 0);
                    if (kk < 3) bc[nt] = Wg[(5 + kk) * 512 + nt * 64 + ln];
                }
                a0 = a0n; a1 = a1n;
            }
        }

        // add gathered top-half + bias, pack, scatter to CSR slots
        {
            float bv[8];
#pragma unroll
            for (int nt = 0; nt < 8; ++nt) bv[nt] = bias[nt * 16 + c15];
#pragma unroll
            for (int m = 0; m < 2; ++m) {
#pragma unroll
                for (int r = 0; r < 4; ++r) {
                    int erow = m * 16 + g * 4 + r;
                    int slot = __shfl(slotv, erow);
                    unsigned* base = (unsigned*)(msg + (size_t)slot * D + (c15 & ~1));
#pragma unroll
                    for (int nt = 0; nt < 8; ++nt) {
                        float v = acc[m][nt][r] + GXT(gm[m][r], nt) + bv[nt];
                        float o = __shfl_xor(v, 1);
                        float lo = (ln & 1) ? o : v;
                        float hi = (ln & 1) ? v : o;
                        unsigned pk = ((unsigned)f2bf(hi) << 16) | f2bf(lo);
                        if ((ln & 1) == (nt >> 2))
                            base[nt * 8] = pk;
                    }
                }
            }
        }
    }
}

// ---------------------------------------------------------------------------
// node_kernel: gather CSR slot range, mean, leaky, +H, LN. f32 accumulate.
// ---------------------------------------------------------------------------
__global__ __launch_bounds__(256)
void node_kernel(const float* __restrict__ Hin, const unsigned short* __restrict__ msg,
                 const int* __restrict__ off, const float* __restrict__ g,
                 const float* __restrict__ b, float* __restrict__ Hout,
                 unsigned short* __restrict__ Hb, int n)
{
    const int wave = threadIdx.x >> 6, lane = threadIdx.x & 63;
    const int node = blockIdx.x * 4 + wave;
    if (node >= n) return;

    const int beg = off[node], end = off[node + 1];
    const float inv = 1.0f / fmaxf((float)(end - beg), 1.0f);
    const unsigned* mb = (const unsigned*)msg;

    float a0 = 0.f, a1 = 0.f;
    int i = beg;
    for (; i + 1 < end; i += 2) {
        unsigned v0 = mb[(size_t)i * 64 + lane];
        unsigned v1 = mb[(size_t)(i + 1) * 64 + lane];
        a0 += bf2f((unsigned short)(v0 & 0xffff)) + bf2f((unsigned short)(v1 & 0xffff));
        a1 += bf2f((unsigned short)(v0 >> 16))    + bf2f((unsigned short)(v1 >> 16));
    }
    if (i < end) {
        unsigned v0 = mb[(size_t)i * 64 + lane];
        a0 += bf2f((unsigned short)(v0 & 0xffff));
        a1 += bf2f((unsigned short)(v0 >> 16));
    }

    a0 *= inv; a1 *= inv;
    a0 = (a0 >= 0.f) ? a0 : SLOPE * a0;
    a1 = (a1 >= 0.f) ? a1 : SLOPE * a1;

    size_t base = (size_t)node * D + 2 * lane;
    float x0 = a0 + Hin[base];
    float x1 = a1 + Hin[base + 1];

    float s = x0 + x1, ss = x0 * x0 + x1 * x1;
#pragma unroll
    for (int d = 1; d < 64; d <<= 1) {
        s  += __shfl_xor(s, d);
        ss += __shfl_xor(ss, d);
    }
    float mu  = s * (1.0f / 128.0f);
    float var = ss * (1.0f / 128.0f) - mu * mu;
    float rs  = rsqrtf(var + EPS);

    float o0 = (x0 - mu) * rs * g[2 * lane]     + b[2 * lane];
    float o1 = (x1 - mu) * rs * g[2 * lane + 1] + b[2 * lane + 1];
    Hout[base]     = o0;
    Hout[base + 1] = o1;
    Hb[base]       = f2bf(o0);
    Hb[base + 1]   = f2bf(o1);
}

// ---------------------------------------------------------------------------
extern "C" void kernel_launch(void* const* d_in, const int* in_sizes, int n_in,
                              void* d_out, int out_size, void* d_ws, size_t ws_size,
                              hipStream_t stream)
{
    const float* H0   = (const float*)d_in[0];
    const float* E0   = (const float*)d_in[1];
    const int*   ht   = (const int*)d_in[2];
    const float* Weu  = (const float*)d_in[4];
    const float* beu  = (const float*)d_in[5];
    const float* lneg = (const float*)d_in[6];
    const float* lneb = (const float*)d_in[7];
    const float* Wf   = (const float*)d_in[8];
    const float* bfw  = (const float*)d_in[9];
    const float* Wb   = (const float*)d_in[10];
    const float* bbw  = (const float*)d_in[11];
    const float* lnhg = (const float*)d_in[12];
    const float* lnhb = (const float*)d_in[13];

    float* Hout = (float*)d_out;

    // workspace layout (bytes) — total ~518 MB
    char* ws = (char*)d_ws;
    unsigned short* msg    = (unsigned short*)(ws);                  // 256,000,000
    unsigned short* Ebuf   = (unsigned short*)(ws + 256000000);      // 128,000,000
    unsigned short* HW     = (unsigned short*)(ws + 384000000);      // 102,400,000
    unsigned short* Hb     = (unsigned short*)(ws + 486400000);      //  25,600,000
    unsigned short* Weu_sw = (unsigned short*)(ws + 512000000);      //     196,608
    unsigned short* Wf_sw  = (unsigned short*)(ws + 512196608);      //     131,072
    unsigned short* Wb_sw  = (unsigned short*)(ws + 512327680);      //     131,072
    int*            cnt    = (int*)(ws + 512458752);                 //     400,000
    int*            partial= (int*)(ws + 512858752);                 //     400,000
    int*            bsum   = (int*)(ws + 513258752);                 //       2,048
    int*            off    = (int*)(ws + 513260800);                 //     400,016
    int*            pos    = (int*)(ws + 513660816);                 //     400,000
    int*            slotF  = (int*)(ws + 514060816);                 //   2,000,000
    int*            slotB  = (int*)(ws + 516060816);                 //   2,000,000

    wconv_kernel<<<(2*384*128 + 255)/256, 256, 0, stream>>>(Weu, Weu_sw, 384, 2*384*128);
    wconv_kernel<<<(2*256*128 + 255)/256, 256, 0, stream>>>(Wf,  Wf_sw,  256, 2*256*128);
    wconv_kernel<<<(2*256*128 + 255)/256, 256, 0, stream>>>(Wb,  Wb_sw,  256, 2*256*128);
    h2b_kernel<<<(N_NODES * D / 8 + 255)/256, 256, 0, stream>>>(H0, Hb, N_NODES * D / 8);

    // ---- CSR build ----
    const int nscan = (N_NODES + 255) / 256;   // 391
    hipMemsetAsync(cnt, 0, (size_t)N_NODES * sizeof(int), stream);
    count_kernel<<<(M_EDGES + 255) / 256, 256, 0, stream>>>(ht, cnt, M_EDGES);
    scanA_kernel<<<nscan, 256, 0, stream>>>(cnt, partial, bsum, N_NODES);
    scanB_kernel<<<1, 512, 0, stream>>>(bsum, nscan);
    scanC_kernel<<<nscan, 256, 0, stream>>>(partial, bsum, off, pos, N_NODES);
    fill_kernel<<<(M_EDGES + 255) / 256, 256, 0, stream>>>(ht, pos, slotF, slotB, M_EDGES);

    const int hwblocks = ((N_NODES + 127) / 128) * 4;   // 782 * 4 = 3128
    const int eblocks  = M_EDGES / 32;                  // 15625 exact

    for (int l = 0; l < 2; ++l) {
        const float* Hin = (l == 0) ? H0 : Hout;
        const unsigned short* WeuL = Weu_sw + (size_t)l * 49152;
        const unsigned short* WfL  = Wf_sw  + (size_t)l * 32768;
        const unsigned short* WbL  = Wb_sw  + (size_t)l * 32768;

        // dense HW = Hb @ [Wa | Wc | Wf_top | Wb_top]
        hw_kernel<<<hwblocks, 256, 0, stream>>>(
            Hb, WeuL, WeuL + 8 * 4096, WfL, WbL, HW);

        if (l == 0) {
            edge_mfma_kernel<true, true><<<eblocks, 64, 0, stream>>>(
                HW, E0, nullptr, Ebuf, ht, WeuL, WfL, WbL,
                beu, lneg, lneb, bfw, bbw, slotF, slotB, msg);
        } else {
            edge_mfma_kernel<false, false><<<eblocks, 64, 0, stream>>>(
                HW, nullptr, Ebuf, nullptr, ht, WeuL, WfL, WbL,
                beu + D, lneg + D, lneb + D, bfw + D, bbw + D, slotF, slotB, msg);
        }

        node_kernel<<<(N_NODES + 3) / 4, 256, 0, stream>>>(
            Hin, msg, off, lnhg + (size_t)l * D, lnhb + (size_t)l * D, Hout, Hb, N_NODES);
    }
}